// Round 5
// baseline (306.083 us; speedup 1.0000x reference)
//
#include <hip/hip_runtime.h>

// Shapes fixed by reference setup_inputs(): B=8, H=W=16, L=64, C=64.
// out[b, p, l, n, c] = E[b, h+dy[n], w+dx[n], l, c]   (0 if neighbor off-grid)
//
// Output-centric gather, restructured for memory-level parallelism:
//   wave  <-> (b, p, l-quad)  -> writes 8 KB as 8 contiguous 1 KiB stores
//   lane's 8 source loads are unconditional (clamped addr) and independent
//   -> 8 loads in flight per wave; zero-select via cndmask (no branches).
// Plain (cached) loads+stores; XCD-chunk swizzle banding input reads per L2.

typedef float f32x4 __attribute__((ext_vector_type(4)));

__global__ __launch_bounds__(256) void patch_gather_ilp(
    const f32x4* __restrict__ in, f32x4* __restrict__ out) {
  // 8192 blocks; bijective XCD chunk swizzle (8192 % 8 == 0):
  // each XCD gets a contiguous range of 1024 blocks = one full batch image
  // (4.2 MB input working set ~ its 4 MB L2).
  unsigned id = (blockIdx.x & 7u) * 1024u + (blockIdx.x >> 3);
  const unsigned lq = id & 3u;          // which 16-l slice
  const unsigned p  = (id >> 2) & 255u; // patch
  const unsigned b  = id >> 10;         // batch
  const unsigned wv = threadIdx.x >> 6; // wave 0..3
  const unsigned ln = threadIdx.x & 63u;
  const unsigned c4 = ln & 15u;         // float4 within channel row
  const unsigned g  = ln >> 4;          // 16-lane group 0..3
  const int h = (int)(p >> 4), w = (int)(p & 15u);
  const unsigned l0 = lq * 16u + wv * 4u;

  constexpr int DY[8] = {-1, -1, -1,  0, 0,  1, 1, 1};
  constexpr int DX[8] = {-1,  0,  1, -1, 1, -1, 0, 1};

  const f32x4 z = {0.f, 0.f, 0.f, 0.f};
  f32x4 v[8];

  // 8 independent, unconditional loads (clamped source address), then select.
  // load j covers output (l' = j>>1, n = (j&1)*4 + g).
#pragma unroll
  for (int j = 0; j < 8; ++j) {
    const unsigned n  = (unsigned)((j & 1) * 4) + g;
    const unsigned lp = l0 + (unsigned)(j >> 1);
    const int hh = h + DY[n];
    const int ww = w + DX[n];
    const bool ok = ((unsigned)hh < 16u) & ((unsigned)ww < 16u);
    const int hc = min(max(hh, 0), 15);
    const int wc = min(max(ww, 0), 15);
    // in flat (float4 units): (b<<18)|(p'<<10)|(l<<4)|c4
    const unsigned src = (b << 18) | ((unsigned)((hc << 4) | wc) << 10) |
                         (lp << 4) | c4;
    const f32x4 t = in[src];
    v[j].x = ok ? t.x : z.x;
    v[j].y = ok ? t.y : z.y;
    v[j].z = ok ? t.z : z.z;
    v[j].w = ok ? t.w : z.w;
  }

  // 8 contiguous 1 KiB wave stores: out flat = (b<<21)|(p<<13)|(l0<<7) + j*64 + ln
  const unsigned ob = (b << 21) | (p << 13) | (l0 << 7);
#pragma unroll
  for (int j = 0; j < 8; ++j) {
    out[ob + (unsigned)j * 64u + ln] = v[j];
  }
}

extern "C" void kernel_launch(void* const* d_in, const int* in_sizes, int n_in,
                              void* d_out, int out_size, void* d_ws, size_t ws_size,
                              hipStream_t stream) {
  const f32x4* in = (const f32x4*)d_in[0];
  f32x4* out = (f32x4*)d_out;
  patch_gather_ilp<<<8192, 256, 0, stream>>>(in, out);
}

// Round 8
// 286.903 us; speedup vs baseline: 1.0669x; 1.0669x over previous
//
#include <hip/hip_runtime.h>

// Shapes fixed by reference setup_inputs(): B=8, H=W=16, L=64, C=64.
// out[b, p, l, n, c] = E[b, h+dy[n], w+dx[n], l, c]   (0 if neighbor off-grid)
//
// Inverted dataflow (R2 structure, winner at 283 us): one thread per input
// float4 (read exactly once, coalesced, nontemporal), scatter-store it to the
// <=8 output rows that reference it; zero-fill this thread's OWN patch rows
// whose neighbor is off-grid. The two destination sets are disjoint and cover
// every output float4 exactly once (d_out is poisoned before every launch).
//
// R6 change vs R2 (single-variable A/B): data/zero stores are PLAIN cached
// stores instead of __builtin_nontemporal_store — the harness fill kernel
// sustains 6.37 TB/s with plain stores, testing whether nt was the handicap.
// All branches are wave-uniform (p is uniform per 256-thread block).

typedef float f32x4 __attribute__((ext_vector_type(4)));

constexpr unsigned IN4 = 8u * 256u * 64u * 16u;  // 2^21 input float4s

__global__ __launch_bounds__(256) void patch_scatter_plain(
    const f32x4* __restrict__ in, f32x4* __restrict__ out) {
  const unsigned i = blockIdx.x * 256u + threadIdx.x;  // input float4 index
  // in flat (float4 units): (b<<18) | (p<<10) | (l<<4) | c4
  const unsigned c4 = i & 15u;
  const unsigned l  = (i >> 4) & 63u;
  const unsigned p  = (i >> 10) & 255u;
  const unsigned b  = i >> 18;
  const int h = (int)(p >> 4);
  const int w = (int)(p & 15u);

  const f32x4 v = __builtin_nontemporal_load(&in[i]);
  const f32x4 z = {0.f, 0.f, 0.f, 0.f};

  // out flat (float4 units): (b<<21) | (p'<<13) | (l<<7) | (n<<4) | c4
  const unsigned obase = (b << 21) | (l << 7) | c4;
  const unsigned zbase = obase | (p << 13);

  constexpr int DY[8] = {-1, -1, -1,  0, 0,  1, 1, 1};
  constexpr int DX[8] = {-1,  0,  1, -1, 1, -1, 0, 1};
#pragma unroll
  for (int n = 0; n < 8; ++n) {
    // data scatter: output rows (p' = (h-dy, w-dx), n) read this input row
    const int hh = h - DY[n];
    const int ww = w - DX[n];
    if (((unsigned)hh < 16u) & ((unsigned)ww < 16u)) {
      const unsigned dst =
          obase | ((unsigned)((hh << 4) | ww) << 13) | ((unsigned)n << 4);
      out[dst] = v;
    }
    // zero-fill: this thread's own patch row (p, n) if neighbor off-grid
    const int h2 = h + DY[n];
    const int w2 = w + DX[n];
    if (!(((unsigned)h2 < 16u) & ((unsigned)w2 < 16u))) {
      out[zbase | ((unsigned)n << 4)] = z;
    }
  }
}

extern "C" void kernel_launch(void* const* d_in, const int* in_sizes, int n_in,
                              void* d_out, int out_size, void* d_ws, size_t ws_size,
                              hipStream_t stream) {
  const f32x4* in = (const f32x4*)d_in[0];
  f32x4* out = (f32x4*)d_out;
  patch_scatter_plain<<<IN4 / 256u, 256, 0, stream>>>(in, out);
}